// Round 7
// baseline (1019.272 us; speedup 1.0000x reference)
//
#include <hip/hip_runtime.h>
#include <hip/hip_bf16.h>

// Problem constants: B=64, S=512, E=512, H=512, V=32000, T=2, L=1
// Output depends ONLY on batch sample 63 (lstm_out[-1] == last batch element).

#define NB 64   // persistent blocks for the recurrence

// LDS h-buffer swizzle: 32 groups of 16 floats, padded to stride 20 words
// (80 B) -> float4 reads stay 16B-aligned, breaks power-of-2 bank stride.
#define HIDX(e) ((((e) >> 4) * 20) + ((e) & 15))

// ---------------------------------------------------------------------------
// Kernel 1: xg[t][g] = sum_e emb[sent[63][t]][e] * W_ih[g][e] + b_ih[g]+b_hh[g]
// M=512 (t), N=2048 (g), K=512. Epilogue writes BLOCK-LOCAL layout:
//   xg[t*2048 + bb*32 + q*8 + jj]   where g = q*512 + bb*8 + jj
// so each lstm block reads one contiguous 128B line per step.
// ---------------------------------------------------------------------------
__global__ __launch_bounds__(256) void xg_gemm_k(
    const int* __restrict__ sent, const float* __restrict__ emb,
    const float* __restrict__ W_ih, const float* __restrict__ b_ih,
    const float* __restrict__ b_hh, float* __restrict__ xg)
{
    __shared__ float As[16][65];   // [k][m]
    __shared__ float Bs[16][65];   // [k][n]
    __shared__ int aidx[64];
    const int tid = threadIdx.x;
    const int t0 = blockIdx.x * 64;
    const int n0 = blockIdx.y * 64;
    if (tid < 64) aidx[tid] = sent[63 * 512 + t0 + tid];
    __syncthreads();

    const int kk = tid & 15;   // k within tile
    const int mm = tid >> 4;   // 0..15
    const int tx = tid & 15, ty = tid >> 4;
    float acc[4][4] = {};

    for (int kb = 0; kb < 512; kb += 16) {
        #pragma unroll
        for (int j = 0; j < 4; j++) {
            int m = mm + j * 16;
            As[kk][m] = emb[(size_t)aidx[m] * 512 + kb + kk];
            Bs[kk][m] = W_ih[(size_t)(n0 + m) * 512 + kb + kk];
        }
        __syncthreads();
        #pragma unroll
        for (int k = 0; k < 16; k++) {
            float a[4], bv[4];
            #pragma unroll
            for (int i = 0; i < 4; i++) a[i] = As[k][ty * 4 + i];
            #pragma unroll
            for (int j = 0; j < 4; j++) bv[j] = Bs[k][tx * 4 + j];
            #pragma unroll
            for (int i = 0; i < 4; i++)
                #pragma unroll
                for (int j = 0; j < 4; j++)
                    acc[i][j] += a[i] * bv[j];
        }
        __syncthreads();
    }

    #pragma unroll
    for (int i = 0; i < 4; i++) {
        int t = t0 + ty * 4 + i;
        #pragma unroll
        for (int j = 0; j < 4; j++) {
            int col = n0 + tx * 4 + j;
            int q = col >> 9, bb = (col >> 3) & 63, jj = col & 7;
            xg[(size_t)t * 2048 + bb * 32 + q * 8 + jj] =
                acc[i][j] + b_ih[col] + b_hh[col];
        }
    }
}

// ---------------------------------------------------------------------------
// Kernel 2: persistent batch-1 LSTM recurrence, 512 steps, 64 blocks x 256.
// Block b owns h-indices [b*8, b*8+8). Thread (cg = tid&31, rg = tid>>5)
// computes ALL FOUR gates of h-index j=rg over cols cg*16..+15; xor-butterfly
// over the 32 cg lanes; every lane runs the gate tail redundantly with c in
// a register; cg==0 lanes publish. ONE barrier per step.
//
// R7 change (from R6 post-mortem: step time invariant at ~3925 cy across all
// compute-side changes => handoff-bound; hypothesis = LLC same-line
// contention from 256 waves sweeping the same 4KB slot region every poll
// iteration): ONLY WAVE 0 POLLS. Lane L polls exactly block L's 8 tagged
// slots (the poll IS the data read), extracts payloads, ds_writes them to
// hbuf; one __syncthreads releases waves 1-3, whose weight/xg prefetches
// overlap the wait. Reads-per-line-per-period drop ~4x.
//
// Handoff protocol (unchanged): tagged 64-bit slots
//   slot = (uint64)(t+1) << 32 | float_bits(h_t)
// relaxed agent-scope 8B atomics (LLC coherence point), ping-pong sA/sB by
// step parity. No fences, no flags, no producer-side ordering needed (each
// slot is self-contained).
// hbuf is double-buffered by parity: wave0 stages t+2 into the same buffer
// only after barrier(t+1), which requires all waves done with compute(t).
// ---------------------------------------------------------------------------
__global__ __launch_bounds__(256, 1) void lstm_seq_k(
    const float* __restrict__ h0, const float* __restrict__ c0,
    const float* __restrict__ W_hh, const float* __restrict__ xg,
    float* __restrict__ hs,
    unsigned long long* __restrict__ sA,
    unsigned long long* __restrict__ sB)
{
    __shared__ float lw[32 * 512];      // 64 KB weight slice
    __shared__ float hbufA[32 * 20];    // h staging, parity 0
    __shared__ float hbufB[32 * 20];    // h staging, parity 1

    const int tid = threadIdx.x;
    const int b = blockIdx.x;
    const int cg = tid & 31;
    const int rg = tid >> 5;            // this thread's h-index j = rg
    const int hidx = b * 8 + rg;        // global h index

    // --- one-time: stage this block's 32 W_hh rows into LDS ---
    // Layout for conflict-free-ish ds_read_b128:
    //   lw[(lr*4 + kq)*128 + cg*4 + e] = W_hh[row lr][col cg*16 + kq*4 + e]
    {
        const int lr  = tid >> 3;       // local row 0..31  (lr = q*8 + jj)
        const int seg = tid & 7;        // 64-col segment
        const int q   = lr >> 3;
        const int jj  = lr & 7;
        const float* src = &W_hh[(size_t)(q * 512 + b * 8 + jj) * 512 + seg * 64];
        #pragma unroll
        for (int f = 0; f < 16; f++) {
            float4 v = *(const float4*)&src[f * 4];
            int c0i = seg * 64 + f * 4;
            int kq  = (c0i & 15) >> 2;
            int cg4 = (c0i >> 4) * 4;
            *(float4*)&lw[(size_t)(lr * 4 + kq) * 128 + cg4] = v;
        }
    }

    float creg = c0[63 * 512 + hidx];   // cell state, per-thread register
    __syncthreads();

    for (int t = 0; t < 512; t++) {
        float* hb = (t & 1) ? hbufB : hbufA;

        // ---- prefetch (overlaps the wait): weight fragment + xg line ----
        float4 wv[4][4];
        #pragma unroll
        for (int q = 0; q < 4; q++) {
            const float* wrow = &lw[(size_t)((q * 8 + rg) * 4) * 128 + cg * 4];
            #pragma unroll
            for (int kq = 0; kq < 4; kq++)
                wv[q][kq] = *(const float4*)&wrow[kq * 128];
        }
        float xgp[4];
        #pragma unroll
        for (int q = 0; q < 4; q++)
            xgp[q] = xg[(size_t)t * 2048 + b * 32 + q * 8 + rg];
        asm volatile("" ::: "memory");   // issue prefetches before the wait

        // ---- wave 0 only: poll + stage h_{t-1} ----
        if (tid < 64) {
            const int L = tid;                      // lane = source block id
            const int wbase = (L >> 1) * 20 + (L & 1) * 8;  // HIDX(8L) words
            if (t == 0) {
                float4 a = *(const float4*)&h0[63 * 512 + L * 8];
                float4 c = *(const float4*)&h0[63 * 512 + L * 8 + 4];
                *(float4*)&hb[wbase]     = a;
                *(float4*)&hb[wbase + 4] = c;
            } else {
                unsigned long long* src = ((t - 1) & 1) ? sB : sA;
                const unsigned long long* p = &src[L * 8];
                const unsigned int expt = (unsigned int)t;
                unsigned long long s0, s1, s2, s3, s4, s5, s6, s7;
                for (;;) {
                    s0 = __hip_atomic_load(&p[0], __ATOMIC_RELAXED, __HIP_MEMORY_SCOPE_AGENT);
                    s1 = __hip_atomic_load(&p[1], __ATOMIC_RELAXED, __HIP_MEMORY_SCOPE_AGENT);
                    s2 = __hip_atomic_load(&p[2], __ATOMIC_RELAXED, __HIP_MEMORY_SCOPE_AGENT);
                    s3 = __hip_atomic_load(&p[3], __ATOMIC_RELAXED, __HIP_MEMORY_SCOPE_AGENT);
                    s4 = __hip_atomic_load(&p[4], __ATOMIC_RELAXED, __HIP_MEMORY_SCOPE_AGENT);
                    s5 = __hip_atomic_load(&p[5], __ATOMIC_RELAXED, __HIP_MEMORY_SCOPE_AGENT);
                    s6 = __hip_atomic_load(&p[6], __ATOMIC_RELAXED, __HIP_MEMORY_SCOPE_AGENT);
                    s7 = __hip_atomic_load(&p[7], __ATOMIC_RELAXED, __HIP_MEMORY_SCOPE_AGENT);
                    if ((unsigned int)(s0 >> 32) == expt && (unsigned int)(s1 >> 32) == expt &&
                        (unsigned int)(s2 >> 32) == expt && (unsigned int)(s3 >> 32) == expt &&
                        (unsigned int)(s4 >> 32) == expt && (unsigned int)(s5 >> 32) == expt &&
                        (unsigned int)(s6 >> 32) == expt && (unsigned int)(s7 >> 32) == expt)
                        break;
                }
                float4 a, c;
                a.x = __uint_as_float((unsigned int)s0);
                a.y = __uint_as_float((unsigned int)s1);
                a.z = __uint_as_float((unsigned int)s2);
                a.w = __uint_as_float((unsigned int)s3);
                c.x = __uint_as_float((unsigned int)s4);
                c.y = __uint_as_float((unsigned int)s5);
                c.z = __uint_as_float((unsigned int)s6);
                c.w = __uint_as_float((unsigned int)s7);
                *(float4*)&hb[wbase]     = a;
                *(float4*)&hb[wbase + 4] = c;
            }
        }
        __syncthreads();   // the ONLY barrier per step

        // h fragment: 16 consecutive h values from LDS.
        float hvf[16];
        #pragma unroll
        for (int i4 = 0; i4 < 4; i4++) {
            float4 v = *(const float4*)&hb[cg * 20 + i4 * 4];
            hvf[i4 * 4 + 0] = v.x; hvf[i4 * 4 + 1] = v.y;
            hvf[i4 * 4 + 2] = v.z; hvf[i4 * 4 + 3] = v.w;
        }

        // 4 gate rows x 16 cols.
        float acc[4];
        #pragma unroll
        for (int q = 0; q < 4; q++) {
            float s = 0.f;
            #pragma unroll
            for (int kq = 0; kq < 4; kq++) {
                s += wv[q][kq].x * hvf[kq * 4 + 0];
                s += wv[q][kq].y * hvf[kq * 4 + 1];
                s += wv[q][kq].z * hvf[kq * 4 + 2];
                s += wv[q][kq].w * hvf[kq * 4 + 3];
            }
            acc[q] = s;
        }

        // Butterfly over the 32 cg lanes (xor masks <=16 stay within rg half).
        #pragma unroll
        for (int q = 0; q < 4; q++) {
            #pragma unroll
            for (int m = 16; m >= 1; m >>= 1)
                acc[q] += __shfl_xor(acc[q], m, 64);
        }

        // Gate tail, redundantly on all 32 lanes. Torch order: i, f, g, o.
        float gi = acc[0] + xgp[0];
        float gf = acc[1] + xgp[1];
        float gg = acc[2] + xgp[2];
        float go = acc[3] + xgp[3];
        float ii = 1.f / (1.f + __expf(-gi));
        float ff = 1.f / (1.f + __expf(-gf));
        float cc = 1.f - 2.f / (__expf(2.f * gg) + 1.f);   // tanh
        float oo = 1.f / (1.f + __expf(-go));
        creg = ff * creg + ii * cc;
        float th = 1.f - 2.f / (__expf(2.f * creg) + 1.f); // tanh
        float hval = oo * th;

        if (cg == 0) {
            // History for the final linear (plain store, fire-and-forget).
            hs[(size_t)t * 512 + hidx] = hval;
            // Tagged slot: one 8B relaxed agent atomic store -> LLC.
            unsigned long long* dst = (t & 1) ? sB : sA;
            unsigned long long pv =
                ((unsigned long long)(unsigned int)(t + 1) << 32) |
                (unsigned long long)__float_as_uint(hval);
            __hip_atomic_store(&dst[hidx], pv,
                               __ATOMIC_RELAXED, __HIP_MEMORY_SCOPE_AGENT);
        }
    }
}

// ---------------------------------------------------------------------------
// Kernel 3: out[s][u] = hs[s] . W_lin[u] + b_lin[u], S=512, T=2.
// ---------------------------------------------------------------------------
__global__ __launch_bounds__(256) void final_linear_k(
    const float* __restrict__ hs, const float* __restrict__ W_lin,
    const float* __restrict__ b_lin, float* __restrict__ out)
{
    const int tid = threadIdx.x;
    const int wave = tid >> 6;
    const int lane = tid & 63;
    const int s = blockIdx.x * 4 + wave;
    const float* h = hs + (size_t)s * 512;
    float a0 = 0.f, a1 = 0.f;
    #pragma unroll
    for (int k0 = 0; k0 < 512; k0 += 64) {
        float hv = h[k0 + lane];
        a0 += hv * W_lin[k0 + lane];
        a1 += hv * W_lin[512 + k0 + lane];
    }
    #pragma unroll
    for (int m = 32; m >= 1; m >>= 1) {
        a0 += __shfl_xor(a0, m, 64);
        a1 += __shfl_xor(a1, m, 64);
    }
    if (lane == 0) {
        out[s * 2]     = a0 + b_lin[0];
        out[s * 2 + 1] = a1 + b_lin[1];
    }
}

// ---------------------------------------------------------------------------
extern "C" void kernel_launch(void* const* d_in, const int* in_sizes, int n_in,
                              void* d_out, int out_size, void* d_ws, size_t ws_size,
                              hipStream_t stream)
{
    const int*   sent  = (const int*)d_in[0];     // [64,512] int32
    const float* h0    = (const float*)d_in[1];   // [1,64,512]
    const float* c0    = (const float*)d_in[2];   // [1,64,512]
    const float* emb   = (const float*)d_in[3];   // [32000,512]
    const float* W_ih  = (const float*)d_in[4];   // [2048,512]
    const float* W_hh  = (const float*)d_in[5];   // [2048,512]
    const float* b_ih  = (const float*)d_in[6];   // [2048]
    const float* b_hh  = (const float*)d_in[7];   // [2048]
    const float* W_lin = (const float*)d_in[8];   // [2,512]
    const float* b_lin = (const float*)d_in[9];   // [2]
    float* out = (float*)d_out;                   // [512,2]

    char* ws = (char*)d_ws;
    float* xg = (float*)ws;                                   // 4 MB: [512,2048] (block-local layout)
    float* hs = (float*)(ws + 4 * 1024 * 1024);               // 1 MB: [512,512]
    unsigned long long* sA = (unsigned long long*)(ws + 5 * 1024 * 1024);          // 4 KB
    unsigned long long* sB = (unsigned long long*)(ws + 5 * 1024 * 1024 + 4096);   // 4 KB

    // Clear slot tags (0 != any expected tag 1..512).
    hipMemsetAsync(sA, 0, 2 * 4096, stream);

    dim3 g1(8, 32);
    xg_gemm_k<<<g1, 256, 0, stream>>>(sent, emb, W_ih, b_ih, b_hh, xg);
    lstm_seq_k<<<NB, 256, 0, stream>>>(h0, c0, W_hh, xg, hs, sA, sB);
    final_linear_k<<<128, 256, 0, stream>>>(hs, W_lin, b_lin, out);
}